// Round 5
// baseline (476.599 us; speedup 1.0000x reference)
//
#include <hip/hip_runtime.h>
#include <hip/hip_bf16.h>
#include <math.h>

#define BATCHN 8
#define SEQN 4096
#define DMODEL 1024
#define MTOT (BATCHN*SEQN)      // 32768
#define VB_STRIDE 136           // 120 skew params | 16 Bx
#define CHUNKS 128
#define CLEN 32
#define YSIZE ((size_t)MTOT*DMODEL)
#define BN_ROWS 144             // 136 padded to 9*16
#define K1_UNITS 1152           // (hi 144 + lo 144) rows * 4 units of 16B per chunk

typedef __attribute__((ext_vector_type(8))) short short8;
typedef __attribute__((ext_vector_type(4))) float f32x4;

__device__ __forceinline__ unsigned short f2bf(float x){
  __hip_bfloat16 h = __float2bfloat16(x);
  return *(unsigned short*)&h;
}
__device__ __forceinline__ float bf2f(unsigned short b){
  __hip_bfloat16 h; *(unsigned short*)&h = b;
  return __bfloat162float(h);
}

// 16B global->LDS direct DMA (wave-uniform LDS base + lane*16; per-lane global addr)
__device__ __forceinline__ void gload16(unsigned short* lds, const unsigned short* g){
  __builtin_amdgcn_global_load_lds(
      (const __attribute__((address_space(1))) unsigned int*)g,
      (__attribute__((address_space(3))) unsigned int*)lds,
      16, 0, 0);
}

// Wave-local LDS fence: all sharing is within one wave (DS ops are in-order per
// wave), so no s_barrier needed — just compiler fence + LDS-counter drain.
__device__ __forceinline__ void wave_sync(){
  __builtin_amdgcn_sched_barrier(0);
  asm volatile("s_waitcnt lgkmcnt(0)" ::: "memory");
  __builtin_amdgcn_sched_barrier(0);
}

// ---------------- threefry2x32 (partitionable) + XLA erfinv ----------------
__device__ __forceinline__ unsigned rotl32(unsigned x, int d){ return (x<<d)|(x>>(32-d)); }
__device__ __forceinline__ void tfr(unsigned &x0, unsigned &x1, int r){ x0 += x1; x1 = rotl32(x1,r); x1 ^= x0; }

__device__ __forceinline__ float xla_erfinv(float x){
  float w = -log1pf(-x*x);
  float p;
  if (w < 5.0f){
    w = w - 2.5f;
    p = 2.81022636e-08f;
    p = fmaf(p, w, 3.43273939e-07f);
    p = fmaf(p, w, -3.5233877e-06f);
    p = fmaf(p, w, -4.39150654e-06f);
    p = fmaf(p, w, 0.00021858087f);
    p = fmaf(p, w, -0.00125372503f);
    p = fmaf(p, w, -0.00417768164f);
    p = fmaf(p, w, 0.246640727f);
    p = fmaf(p, w, 1.50140941f);
  } else {
    w = sqrtf(w) - 3.0f;
    p = -0.000200214257f;
    p = fmaf(p, w, 0.000100950558f);
    p = fmaf(p, w, 0.00134934322f);
    p = fmaf(p, w, -0.00367342844f);
    p = fmaf(p, w, 0.00573950773f);
    p = fmaf(p, w, -0.0076224613f);
    p = fmaf(p, w, 0.00943887047f);
    p = fmaf(p, w, 1.00167406f);
    p = fmaf(p, w, 2.83297682f);
  }
  return p * x;
}

__device__ float jax_randn(unsigned I){
  unsigned x0 = 0u, x1 = I;
  const unsigned ks2 = 0x1BD11BDBu;
  x0 += 0u; x1 += 1u;
  tfr(x0,x1,13); tfr(x0,x1,15); tfr(x0,x1,26); tfr(x0,x1,6);
  x0 += 1u; x1 += ks2 + 1u;
  tfr(x0,x1,17); tfr(x0,x1,29); tfr(x0,x1,16); tfr(x0,x1,24);
  x0 += ks2; x1 += 0u + 2u;
  tfr(x0,x1,13); tfr(x0,x1,15); tfr(x0,x1,26); tfr(x0,x1,6);
  x0 += 0u; x1 += 1u + 3u;
  tfr(x0,x1,17); tfr(x0,x1,29); tfr(x0,x1,16); tfr(x0,x1,24);
  x0 += 1u; x1 += ks2 + 4u;
  tfr(x0,x1,13); tfr(x0,x1,15); tfr(x0,x1,26); tfr(x0,x1,6);
  x0 += ks2; x1 += 0u + 5u;
  unsigned bits = x0 ^ x1;
  unsigned fb = (bits >> 9) | 0x3f800000u;
  float f = __uint_as_float(fb) - 1.0f;
  const float lo = -0.99999994f;
  float val = f * 2.0f + lo;
  val = fmaxf(lo, val);
  return 1.4142135381698608f * xla_erfinv(val);
}

// ---------------- K0: pre-split [Wp|Bw|0] into bf16 hi/lo, chunk-major UNIT layout ----
__global__ __launch_bounds__(256) void k0_presplit(const float* __restrict__ Wp,
    const float* __restrict__ Bw, unsigned short* __restrict__ Bfrag){
  int i = blockIdx.x*256 + threadIdx.x;      // one thread per 4 elements
  if (i >= BN_ROWS*DMODEL/4) return;
  int n = i >> 8;                            // row 0..143
  int k = (i & 255) * 4;
  float4 t4 = make_float4(0.f,0.f,0.f,0.f);
  if (n < 120)      t4 = *(const float4*)(Wp + (size_t)n*DMODEL + k);
  else if (n < 136) t4 = *(const float4*)(Bw + (size_t)(n-120)*DMODEL + k);
  unsigned short h[4], l[4];
  float v[4] = {t4.x,t4.y,t4.z,t4.w};
  #pragma unroll
  for (int j=0;j<4;j++){
    h[j] = f2bf(v[j]);
    l[j] = f2bf(v[j] - bf2f(h[j]));
  }
  int c  = k >> 5;
  int q  = (k >> 3) & 3;
  int jj = k & 7;                            // 0 or 4
  size_t base = (size_t)c*K1_UNITS*8;
  *(ushort4*)(Bfrag + base + (size_t)(n*4+q)*8 + jj)        = make_ushort4(h[0],h[1],h[2],h[3]);
  *(ushort4*)(Bfrag + base + (size_t)((n+144)*4+q)*8 + jj)  = make_ushort4(l[0],l[1],l[2],l[3]);
}

// ---------------- K1: vb = u @ [Wp|Bw]^T + bias via split-bf16 MFMA ----------------
// v5 (kept from R4): global_load_lds staged B, double-buffered, 1 barrier/chunk.
#define K1_THREADS 512

#define K1_STAGE(C, BUF) do{                                                   \
  const unsigned short* _gB = Bfrag + (size_t)(C)*(K1_UNITS*8);                \
  unsigned short* _l = &Bs[BUF][0];                                            \
  gload16(_l + (wid*64)*8,      _gB + (size_t)(tid)*8);                        \
  gload16(_l + (wid*64+512)*8,  _gB + (size_t)(tid+512)*8);                    \
  if (wid < 2)                                                                 \
    gload16(_l + (wid*64+1024)*8, _gB + (size_t)(tid+1024)*8);                 \
}while(0)

#define K1_ALOAD(C, ARA, ARB) do{                                              \
  const float* _ap = aptr + (C)*32;                                            \
  ARA = *(const float4*)(_ap);                                                 \
  ARB = *(const float4*)(_ap + 4);                                             \
}while(0)

#define K1_COMPUTE(BUF, ARA, ARB) do{                                          \
  short8 _ah, _al;                                                             \
  {                                                                            \
    float _va[8] = {ARA.x,ARA.y,ARA.z,ARA.w,ARB.x,ARB.y,ARB.z,ARB.w};          \
    _Pragma("unroll")                                                          \
    for (int _j=0;_j<8;_j++){                                                  \
      unsigned short _h = f2bf(_va[_j]);                                       \
      _ah[_j] = (short)_h;                                                     \
      _al[_j] = (short)f2bf(_va[_j] - bf2f(_h));                               \
    }                                                                          \
  }                                                                            \
  const unsigned short* _sb = &Bs[BUF][0];                                     \
  _Pragma("unroll")                                                            \
  for (int _t=0;_t<5;_t++){                                                    \
    if (_t < nt){                                                              \
      int _row = (t0+_t)*16 + lrow;                                            \
      short8 _bh = *(const short8*)(_sb + _row*32 + quad*8);                   \
      short8 _bl = *(const short8*)(_sb + (_row+144)*32 + quad*8);             \
      acc[_t] = __builtin_amdgcn_mfma_f32_16x16x32_bf16(_ah, _bh, acc[_t], 0,0,0); \
      acc[_t] = __builtin_amdgcn_mfma_f32_16x16x32_bf16(_ah, _bl, acc[_t], 0,0,0); \
      acc[_t] = __builtin_amdgcn_mfma_f32_16x16x32_bf16(_al, _bh, acc[_t], 0,0,0); \
    }                                                                          \
  }                                                                            \
}while(0)

__global__ __launch_bounds__(512, 4) void k1_mfma(const float* __restrict__ u,
    const unsigned short* __restrict__ Bfrag,
    const float* __restrict__ Wpb, float* __restrict__ vb){
  __shared__ unsigned short Bs[2][K1_UNITS*8];   // 2 x 18KB, linear unit order

  const int tid  = threadIdx.x;
  const int wid  = tid >> 6;
  const int lane = tid & 63;
  const int quad = lane >> 4;
  const int lrow = lane & 15;
  const int wm   = wid & 3;          // row subtile: rows wm*16..+15
  const int wn   = wid >> 2;         // n-group: 0 -> tiles 0..4, 1 -> tiles 5..8
  const int t0   = wn ? 5 : 0;
  const int nt   = wn ? 4 : 5;
  const int m0   = blockIdx.x * 64;

  const float* aptr = u + (size_t)(m0 + wm*16 + lrow)*DMODEL + quad*8;

  f32x4 acc[5];
  #pragma unroll
  for (int t=0;t<5;t++) acc[t] = (f32x4){0.f,0.f,0.f,0.f};

  float4 a0a, a0b, a1a, a1b;

  // prologue: DMA chunk 0 into buf 0; A chunk 0 into set 0
  K1_STAGE(0, 0);
  K1_ALOAD(0, a0a, a0b);
  __syncthreads();                                  // vmcnt(0) drain + barrier

  for (int c=0; c<DMODEL/32; c+=2){
    K1_STAGE(c+1, 1);
    K1_ALOAD(c+1, a1a, a1b);
    K1_COMPUTE(0, a0a, a0b);
    __syncthreads();
    if (c+2 < DMODEL/32){
      K1_STAGE(c+2, 0);
      K1_ALOAD(c+2, a0a, a0b);
    }
    K1_COMPUTE(1, a1a, a1b);
    if (c+2 < DMODEL/32) __syncthreads();
  }

  // ---- store: lane L reg i -> row quad*4+i, col lrow (bias in epilogue) ----
  #pragma unroll
  for (int t=0;t<5;t++){
    if (t < nt){
      int col = (t0+t)*16 + lrow;
      if (col < VB_STRIDE){
        float bias = (col < 120) ? Wpb[col] : 0.f;
        #pragma unroll
        for (int i=0;i<4;i++){
          int row = m0 + wm*16 + quad*4 + i;
          vb[(size_t)row*VB_STRIDE + col] = acc[t][i] + bias;
        }
      }
    }
  }
}

// ---------------- K2: A -> power-iter sigma -> scale -> W ; ortho accum ----------------
// v2: all sharing is within a 16-lane group (= one wave); block barriers replaced
// with wave_sync (no s_barrier, no cross-wave coupling). Only the final gsum
// reduction keeps a real __syncthreads.
__global__ __launch_bounds__(128) void k2_build_w(const float* __restrict__ vb,
    float* __restrict__ Wg, float* __restrict__ ortho){
  __shared__ float Af[8*324];
  __shared__ float Sf[8*324];
  __shared__ float gsum[8];
  const int tid = threadIdx.x;
  const int grp = tid >> 4;
  const int r   = tid & 15;
  const int m   = blockIdx.x*8 + grp;
  float* A = Af + grp*324;
  float* S = Sf + grp*324;
  const float* vrow = vb + (size_t)m*VB_STRIDE;

  // skew row r in registers
  float a_s[16];
  #pragma unroll
  for (int c=0;c<16;c++){
    float val = 0.f;
    if (c > r)      val =  vrow[r*15 - (r*(r-1))/2 + (c-r-1)];
    else if (c < r) val = -vrow[c*15 - (c*(c-1))/2 + (r-c-1)];
    a_s[c] = val;
  }

  // power iteration (register-only): A^T = -A
  float uv = jax_randn((unsigned)m*16u + (unsigned)r);
  float nn = uv*uv;
  #pragma unroll
  for (int s=1;s<16;s<<=1) nn += __shfl_xor(nn, s, 16);
  uv = uv / fmaxf(sqrtf(nn), 1e-12f);

  float t2 = 0.f;
  #pragma unroll
  for (int it=0; it<2; ++it){
    float t1 = 0.f;
    #pragma unroll
    for (int k=0;k<16;k++) t1 += a_s[k]*__shfl(uv, k, 16);
    t1 = -t1;                                   // A^T u
    nn = t1*t1;
    #pragma unroll
    for (int s=1;s<16;s<<=1) nn += __shfl_xor(nn, s, 16);
    float vvec = t1 / fmaxf(sqrtf(nn), 1e-12f);
    t2 = 0.f;
    #pragma unroll
    for (int k=0;k<16;k++) t2 += a_s[k]*__shfl(vvec, k, 16);  // A v
    nn = t2*t2;
    #pragma unroll
    for (int s=1;s<16;s<<=1) nn += __shfl_xor(nn, s, 16);
    uv = t2 / fmaxf(sqrtf(nn), 1e-12f);
  }
  float sig = uv * t2;
  #pragma unroll
  for (int s=1;s<16;s<<=1) sig += __shfl_xor(sig, s, 16);
  sig = fabsf(sig);
  const float scale = 0.3f / fmaxf(sig, 0.3f);
  #pragma unroll
  for (int k=0;k<16;k++) a_s[k] *= scale;

  // write A rows to LDS
  #pragma unroll
  for (int q=0;q<4;q++)
    *(float4*)(A + r*20 + q*4) = make_float4(a_s[q*4],a_s[q*4+1],a_s[q*4+2],a_s[q*4+3]);
  wave_sync();

  // S = A@A (row r): s = sum_k a[k]*Arow(k)
  float s_s[16];
  #pragma unroll
  for (int j=0;j<16;j++) s_s[j] = 0.f;
  #pragma unroll
  for (int k=0;k<16;k++){
    #pragma unroll
    for (int q=0;q<4;q++){
      float4 ak = *(const float4*)(A + k*20 + q*4);
      s_s[q*4+0] = fmaf(a_s[k], ak.x, s_s[q*4+0]);
      s_s[q*4+1] = fmaf(a_s[k], ak.y, s_s[q*4+1]);
      s_s[q*4+2] = fmaf(a_s[k], ak.z, s_s[q*4+2]);
      s_s[q*4+3] = fmaf(a_s[k], ak.w, s_s[q*4+3]);
    }
  }
  #pragma unroll
  for (int q=0;q<4;q++)
    *(float4*)(S + r*20 + q*4) = make_float4(s_s[q*4],s_s[q*4+1],s_s[q*4+2],s_s[q*4+3]);
  wave_sync();

  // AS and SS rows
  float as_s[16], ss_s[16];
  #pragma unroll
  for (int j=0;j<16;j++){ as_s[j]=0.f; ss_s[j]=0.f; }
  #pragma unroll
  for (int k=0;k<16;k++){
    #pragma unroll
    for (int q=0;q<4;q++){
      float4 sk = *(const float4*)(S + k*20 + q*4);
      as_s[q*4+0] = fmaf(a_s[k], sk.x, as_s[q*4+0]);
      as_s[q*4+1] = fmaf(a_s[k], sk.y, as_s[q*4+1]);
      as_s[q*4+2] = fmaf(a_s[k], sk.z, as_s[q*4+2]);
      as_s[q*4+3] = fmaf(a_s[k], sk.w, as_s[q*4+3]);
      ss_s[q*4+0] = fmaf(s_s[k], sk.x, ss_s[q*4+0]);
      ss_s[q*4+1] = fmaf(s_s[k], sk.y, ss_s[q*4+1]);
      ss_s[q*4+2] = fmaf(s_s[k], sk.z, ss_s[q*4+2]);
      ss_s[q*4+3] = fmaf(s_s[k], sk.w, ss_s[q*4+3]);
    }
  }
  // W = I - 2A + 2S - 2AS + SS
  float w_s[16];
  #pragma unroll
  for (int j=0;j<16;j++){
    float wv = -2.f*a_s[j] + 2.f*s_s[j] - 2.f*as_s[j] + ss_s[j];
    if (j == r) wv += 1.f;
    w_s[j] = wv;
  }
  float4* wout = (float4*)(Wg + (size_t)m*256 + r*16);
  #pragma unroll
  for (int q=0;q<4;q++)
    wout[q] = make_float4(w_s[q*4],w_s[q*4+1],w_s[q*4+2],w_s[q*4+3]);

  // ortho dev: reuse A buffer for W (wave-local; DS ops in-order per wave)
  wave_sync();
  #pragma unroll
  for (int q=0;q<4;q++)
    *(float4*)(A + r*20 + q*4) = make_float4(w_s[q*4],w_s[q*4+1],w_s[q*4+2],w_s[q*4+3]);
  wave_sync();
  float wt_s[16];
  #pragma unroll
  for (int j=0;j<16;j++) wt_s[j] = 0.f;
  #pragma unroll
  for (int k=0;k<16;k++){
    float ck = A[k*20 + r];                 // W[k][r]
    #pragma unroll
    for (int q=0;q<4;q++){
      float4 wk = *(const float4*)(A + k*20 + q*4);
      wt_s[q*4+0] = fmaf(ck, wk.x, wt_s[q*4+0]);
      wt_s[q*4+1] = fmaf(ck, wk.y, wt_s[q*4+1]);
      wt_s[q*4+2] = fmaf(ck, wk.z, wt_s[q*4+2]);
      wt_s[q*4+3] = fmaf(ck, wk.w, wt_s[q*4+3]);
    }
  }
  float dev = 0.f;
  #pragma unroll
  for (int j=0;j<16;j++){
    float v = wt_s[j] - ((j==r)?1.f:0.f);
    dev += v*v;
  }
  #pragma unroll
  for (int s=1;s<16;s<<=1) dev += __shfl_xor(dev, s, 16);
  if (r==0) gsum[grp] = sqrtf(dev);
  __syncthreads();                           // cross-wave: keep real barrier
  if (tid==0){
    float t=0.f;
    #pragma unroll
    for (int i=0;i<8;i++) t += gsum[i];
    atomicAdd(ortho, t);
  }
}

// ---------------- K3a: per-chunk reduce in fp64 (single-wave block: wave_sync) ----
__global__ __launch_bounds__(64) void k3a_chunk_reduce(const float* __restrict__ Wg,
    const float* __restrict__ vb, double* __restrict__ Msum){
  const int chunk = blockIdx.x;
  const int b = chunk / CHUNKS, c = chunk - b*CHUNKS;
  const int lane = threadIdx.x, r = lane & 15, g = lane >> 4;
  __shared__ double Mb[2][16*20];
  __shared__ double sb[16];
  #pragma unroll
  for (int cc=0;cc<4;cc++) Mb[0][r*20 + 4*g + cc] = (r == 4*g+cc) ? 1.0 : 0.0;
  if (lane < 16) sb[lane] = 0.0;
  wave_sync();
  const size_t mbase = (size_t)b*SEQN + (size_t)c*CLEN;
  float4 wq = *(const float4*)(Wg + mbase*256 + r*16 + 4*g);
  float bx = vb[mbase*VB_STRIDE + 120 + r];
  int p = 0;
  for (int t=0;t<CLEN;++t){
    float4 wn = make_float4(0.f,0.f,0.f,0.f); float bxn = 0.f;
    if (t+1 < CLEN){
      wn  = *(const float4*)(Wg + (mbase+t+1)*256 + r*16 + 4*g);
      bxn = vb[(mbase+t+1)*VB_STRIDE + 120 + r];
    }
    const double* M = Mb[p];
    double a0=0.0,a1=0.0,a2=0.0,a3=0.0, sacc=0.0;
    #pragma unroll
    for (int kg=0;kg<4;kg++){
      float wk0 = __shfl(wq.x, r + 16*kg);
      float wk1 = __shfl(wq.y, r + 16*kg);
      float wk2 = __shfl(wq.z, r + 16*kg);
      float wk3 = __shfl(wq.w, r + 16*kg);
      float wkv[4] = {wk0,wk1,wk2,wk3};
      #pragma unroll
      for (int e=0;e<4;e++){
        int k = 4*kg + e;
        double w = (double)wkv[e];
        const double* mrow = M + k*20 + 4*g;
        a0 = fma(w, mrow[0], a0);
        a1 = fma(w, mrow[1], a1);
        a2 = fma(w, mrow[2], a2);
        a3 = fma(w, mrow[3], a3);
        sacc = fma(w, sb[k], sacc);
      }
    }
    wave_sync();
    double* Mn = Mb[1-p];
    Mn[r*20+4*g+0]=a0; Mn[r*20+4*g+1]=a1; Mn[r*20+4*g+2]=a2; Mn[r*20+4*g+3]=a3;
    if (g==0) sb[r] = sacc + (double)bx;
    wave_sync();
    p ^= 1;
    wq = wn; bx = bxn;
  }
  double* out = Msum + (size_t)chunk*272;
  #pragma unroll
  for (int cc=0;cc<4;cc++) out[r*16+4*g+cc] = Mb[p][r*20+4*g+cc];
  if (lane<16) out[256+lane] = sb[lane];
}

// ---------------- K3b: exclusive affine prefix over chunk summaries, fp64 ----------------
__global__ __launch_bounds__(64) void k3b_prefix(const double* __restrict__ Msum,
    double* __restrict__ hstart){
  const int b = blockIdx.x;
  const int lane = threadIdx.x, r = lane & 15, g = lane >> 4;
  __shared__ double q[16];
  if (lane < 16) q[lane] = 0.0;
  wave_sync();
  const double* base = Msum + (size_t)b*CHUNKS*272;
  double2 m01 = *(const double2*)(base + r*16 + 4*g);
  double2 m23 = *(const double2*)(base + r*16 + 4*g + 2);
  double sv = base[256 + r];
  for (int c=0;c<CHUNKS;++c){
    double2 n01, n23; double svn = 0.0;
    n01.x=n01.y=n23.x=n23.y=0.0;
    if (c+1 < CHUNKS){
      const double* bn = base + (size_t)(c+1)*272;
      n01 = *(const double2*)(bn + r*16 + 4*g);
      n23 = *(const double2*)(bn + r*16 + 4*g + 2);
      svn = bn[256 + r];
    }
    if (lane < 16) hstart[((size_t)b*CHUNKS + c)*16 + lane] = q[lane];
    double part = m01.x*q[4*g+0] + m01.y*q[4*g+1] + m23.x*q[4*g+2] + m23.y*q[4*g+3];
    part += __shfl_xor(part, 16);
    part += __shfl_xor(part, 32);
    wave_sync();
    if (g==0) q[r] = part + sv;
    wave_sync();
    m01 = n01; m23 = n23; sv = svn;
  }
}

// ---------------- K3c: re-apply within chunk, fp64 state ----------------
__global__ __launch_bounds__(64) void k3c_apply(const float* __restrict__ Wg,
    const float* __restrict__ vb, const double* __restrict__ hstart,
    float* __restrict__ hout){
  const int chunk = blockIdx.x;
  const int b = chunk / CHUNKS, c = chunk - b*CHUNKS;
  const int lane = threadIdx.x, r = lane & 15, g = lane >> 4;
  __shared__ double h[16];
  if (lane < 16) h[lane] = hstart[(size_t)chunk*16 + lane];
  wave_sync();
  const size_t mbase = (size_t)b*SEQN + (size_t)c*CLEN;
  float4 wq = *(const float4*)(Wg + mbase*256 + r*16 + 4*g);
  float bx = vb[mbase*VB_STRIDE + 120 + r];
  for (int t=0;t<CLEN;++t){
    float4 wn = make_float4(0.f,0.f,0.f,0.f); float bxn = 0.f;
    if (t+1 < CLEN){
      wn  = *(const float4*)(Wg + (mbase+t+1)*256 + r*16 + 4*g);
      bxn = vb[(mbase+t+1)*VB_STRIDE + 120 + r];
    }
    double part = (double)wq.x*h[4*g+0] + (double)wq.y*h[4*g+1]
                + (double)wq.z*h[4*g+2] + (double)wq.w*h[4*g+3];
    part += __shfl_xor(part, 16);
    part += __shfl_xor(part, 32);
    wave_sync();
    if (g==0){
      double nh = part + (double)bx;
      h[r] = nh;
      hout[(mbase+t)*16 + r] = (float)nh;
    }
    wave_sync();
    wq = wn; bx = bxn;
  }
}

// ---------------- K4: y = h @ C^T + u*D ; append ortho_dev ----------------
__device__ __forceinline__ float dot4f(float4 a, float4 b){
  return a.x*b.x + a.y*b.y + a.z*b.z + a.w*b.w;
}

__global__ __launch_bounds__(256) void k4_out(const float* __restrict__ hbuf,
    const float* __restrict__ u, const float* __restrict__ Cw,
    const float* __restrict__ D, const float* __restrict__ ortho,
    float* __restrict__ y, int write_ortho){
  __shared__ float hl[256];
  const int m0 = blockIdx.x * 16;
  hl[threadIdx.x] = hbuf[(size_t)m0*16 + threadIdx.x];
  __syncthreads();
  const int col = threadIdx.x * 4;
  float4 cm[4][4];
  #pragma unroll
  for (int cc=0;cc<4;cc++)
    #pragma unroll
    for (int jj=0;jj<4;jj++)
      cm[cc][jj] = *(const float4*)(Cw + (size_t)(col+cc)*16 + jj*4);
  float4 d4 = *(const float4*)(D + col);
  #pragma unroll
  for (int row=0;row<16;row++){
    const float4* hr = (const float4*)(hl + row*16);
    float4 h0=hr[0], h1=hr[1], h2=hr[2], h3=hr[3];
    float4 o;
    o.x = dot4f(cm[0][0],h0)+dot4f(cm[0][1],h1)+dot4f(cm[0][2],h2)+dot4f(cm[0][3],h3);
    o.y = dot4f(cm[1][0],h0)+dot4f(cm[1][1],h1)+dot4f(cm[1][2],h2)+dot4f(cm[1][3],h3);
    o.z = dot4f(cm[2][0],h0)+dot4f(cm[2][1],h1)+dot4f(cm[2][2],h2)+dot4f(cm[2][3],h3);
    o.w = dot4f(cm[3][0],h0)+dot4f(cm[3][1],h1)+dot4f(cm[3][2],h2)+dot4f(cm[3][3],h3);
    size_t off = (size_t)(m0+row)*DMODEL + col;
    float4 u4 = *(const float4*)(u + off);
    o.x += u4.x*d4.x; o.y += u4.y*d4.y; o.z += u4.z*d4.z; o.w += u4.w*d4.w;
    *(float4*)(y + off) = o;
  }
  if (write_ortho && blockIdx.x==0 && threadIdx.x==0)
    y[YSIZE] = ortho[0] * (1.0f/32768.0f);
}

// ---------------- launcher ----------------
extern "C" void kernel_launch(void* const* d_in, const int* in_sizes, int n_in,
                              void* d_out, int out_size, void* d_ws, size_t ws_size,
                              hipStream_t stream){
  const float* u   = (const float*)d_in[0];
  const float* Wp  = (const float*)d_in[1];
  const float* Wpb = (const float*)d_in[2];
  const float* Bw  = (const float*)d_in[3];
  const float* Cw  = (const float*)d_in[4];
  const float* D   = (const float*)d_in[5];
  float* y = (float*)d_out;

  float* f      = (float*)d_ws;
  float* vb     = f;                                    // 32768*136 f
  float* Wg     = vb  + (size_t)MTOT*VB_STRIDE;         // 32768*256 f
  float* hbuf   = Wg  + (size_t)MTOT*256;               // 32768*16 f
  double* Msum  = (double*)(hbuf + (size_t)MTOT*16);    // BATCHN*CHUNKS*272 d
  double* hstart= Msum + (size_t)BATCHN*CHUNKS*272;     // BATCHN*CHUNKS*16 d
  unsigned short* Bfrag = (unsigned short*)(hstart + (size_t)BATCHN*CHUNKS*16); // 32*1152*8 us
  float* ortho  = (float*)(Bfrag + (size_t)32*K1_UNITS*8);

  int write_ortho = ((size_t)out_size > YSIZE) ? 1 : 0;

  hipMemsetAsync(ortho, 0, sizeof(float), stream);
  hipLaunchKernelGGL(k0_presplit,     dim3((BN_ROWS*DMODEL/4+255)/256), dim3(256), 0, stream, Wp, Bw, Bfrag);
  hipLaunchKernelGGL(k1_mfma,         dim3(MTOT/64), dim3(K1_THREADS), 0, stream, u, Bfrag, Wpb, vb);
  hipLaunchKernelGGL(k2_build_w,      dim3(MTOT/8), dim3(128), 0, stream, vb, Wg, ortho);
  hipLaunchKernelGGL(k3a_chunk_reduce,dim3(BATCHN*CHUNKS), dim3(64), 0, stream, Wg, vb, Msum);
  hipLaunchKernelGGL(k3b_prefix,      dim3(BATCHN), dim3(64), 0, stream, Msum, hstart);
  hipLaunchKernelGGL(k3c_apply,       dim3(BATCHN*CHUNKS), dim3(64), 0, stream, Wg, vb, hstart, hbuf);
  hipLaunchKernelGGL(k4_out,          dim3(MTOT/16), dim3(256), 0, stream, hbuf, u, Cw, D, ortho, y, write_ortho);
}

// Round 6
// 462.583 us; speedup vs baseline: 1.0303x; 1.0303x over previous
//
#include <hip/hip_runtime.h>
#include <hip/hip_bf16.h>
#include <math.h>

#define BATCHN 8
#define SEQN 4096
#define DMODEL 1024
#define MTOT (BATCHN*SEQN)      // 32768
#define VB_STRIDE 136           // 120 skew params | 16 Bx
#define CHUNKS 128
#define CLEN 32
#define YSIZE ((size_t)MTOT*DMODEL)
#define BN_ROWS 144             // 136 padded to 9*16
#define K1_UNITS 1152           // (hi 144 + lo 144) rows * 4 units of 16B per chunk

typedef __attribute__((ext_vector_type(8))) short short8;
typedef __attribute__((ext_vector_type(4))) float f32x4;

__device__ __forceinline__ unsigned short f2bf(float x){
  __hip_bfloat16 h = __float2bfloat16(x);
  return *(unsigned short*)&h;
}
__device__ __forceinline__ float bf2f(unsigned short b){
  __hip_bfloat16 h; *(unsigned short*)&h = b;
  return __bfloat162float(h);
}

// 16B global->LDS direct DMA (wave-uniform LDS base + lane*16; per-lane global addr)
__device__ __forceinline__ void gload16(unsigned short* lds, const unsigned short* g){
  __builtin_amdgcn_global_load_lds(
      (const __attribute__((address_space(1))) unsigned int*)g,
      (__attribute__((address_space(3))) unsigned int*)lds,
      16, 0, 0);
}

// Wave-local LDS fence (k2 only: all sharing is within one wave; DS ops are
// in-order per wave) — compiler fence + LDS-counter drain, no s_barrier.
__device__ __forceinline__ void wave_sync(){
  __builtin_amdgcn_sched_barrier(0);
  asm volatile("s_waitcnt lgkmcnt(0)" ::: "memory");
  __builtin_amdgcn_sched_barrier(0);
}

// ---------------- threefry2x32 (partitionable) + XLA erfinv ----------------
__device__ __forceinline__ unsigned rotl32(unsigned x, int d){ return (x<<d)|(x>>(32-d)); }
__device__ __forceinline__ void tfr(unsigned &x0, unsigned &x1, int r){ x0 += x1; x1 = rotl32(x1,r); x1 ^= x0; }

__device__ __forceinline__ float xla_erfinv(float x){
  float w = -log1pf(-x*x);
  float p;
  if (w < 5.0f){
    w = w - 2.5f;
    p = 2.81022636e-08f;
    p = fmaf(p, w, 3.43273939e-07f);
    p = fmaf(p, w, -3.5233877e-06f);
    p = fmaf(p, w, -4.39150654e-06f);
    p = fmaf(p, w, 0.00021858087f);
    p = fmaf(p, w, -0.00125372503f);
    p = fmaf(p, w, -0.00417768164f);
    p = fmaf(p, w, 0.246640727f);
    p = fmaf(p, w, 1.50140941f);
  } else {
    w = sqrtf(w) - 3.0f;
    p = -0.000200214257f;
    p = fmaf(p, w, 0.000100950558f);
    p = fmaf(p, w, 0.00134934322f);
    p = fmaf(p, w, -0.00367342844f);
    p = fmaf(p, w, 0.00573950773f);
    p = fmaf(p, w, -0.0076224613f);
    p = fmaf(p, w, 0.00943887047f);
    p = fmaf(p, w, 1.00167406f);
    p = fmaf(p, w, 2.83297682f);
  }
  return p * x;
}

__device__ float jax_randn(unsigned I){
  unsigned x0 = 0u, x1 = I;
  const unsigned ks2 = 0x1BD11BDBu;
  x0 += 0u; x1 += 1u;
  tfr(x0,x1,13); tfr(x0,x1,15); tfr(x0,x1,26); tfr(x0,x1,6);
  x0 += 1u; x1 += ks2 + 1u;
  tfr(x0,x1,17); tfr(x0,x1,29); tfr(x0,x1,16); tfr(x0,x1,24);
  x0 += ks2; x1 += 0u + 2u;
  tfr(x0,x1,13); tfr(x0,x1,15); tfr(x0,x1,26); tfr(x0,x1,6);
  x0 += 0u; x1 += 1u + 3u;
  tfr(x0,x1,17); tfr(x0,x1,29); tfr(x0,x1,16); tfr(x0,x1,24);
  x0 += 1u; x1 += ks2 + 4u;
  tfr(x0,x1,13); tfr(x0,x1,15); tfr(x0,x1,26); tfr(x0,x1,6);
  x0 += ks2; x1 += 0u + 5u;
  unsigned bits = x0 ^ x1;
  unsigned fb = (bits >> 9) | 0x3f800000u;
  float f = __uint_as_float(fb) - 1.0f;
  const float lo = -0.99999994f;
  float val = f * 2.0f + lo;
  val = fmaxf(lo, val);
  return 1.4142135381698608f * xla_erfinv(val);
}

// ---------------- K0: pre-split [Wp|Bw|0] into bf16 hi/lo, chunk-major UNIT layout ----
__global__ __launch_bounds__(256) void k0_presplit(const float* __restrict__ Wp,
    const float* __restrict__ Bw, unsigned short* __restrict__ Bfrag){
  int i = blockIdx.x*256 + threadIdx.x;      // one thread per 4 elements
  if (i >= BN_ROWS*DMODEL/4) return;
  int n = i >> 8;                            // row 0..143
  int k = (i & 255) * 4;
  float4 t4 = make_float4(0.f,0.f,0.f,0.f);
  if (n < 120)      t4 = *(const float4*)(Wp + (size_t)n*DMODEL + k);
  else if (n < 136) t4 = *(const float4*)(Bw + (size_t)(n-120)*DMODEL + k);
  unsigned short h[4], l[4];
  float v[4] = {t4.x,t4.y,t4.z,t4.w};
  #pragma unroll
  for (int j=0;j<4;j++){
    h[j] = f2bf(v[j]);
    l[j] = f2bf(v[j] - bf2f(h[j]));
  }
  int c  = k >> 5;
  int q  = (k >> 3) & 3;
  int jj = k & 7;                            // 0 or 4
  size_t base = (size_t)c*K1_UNITS*8;
  *(ushort4*)(Bfrag + base + (size_t)(n*4+q)*8 + jj)        = make_ushort4(h[0],h[1],h[2],h[3]);
  *(ushort4*)(Bfrag + base + (size_t)((n+144)*4+q)*8 + jj)  = make_ushort4(l[0],l[1],l[2],l[3]);
}

// ---------------- K1: vb = u @ [Wp|Bw]^T + bias via split-bf16 MFMA ----------------
// (kept from R4): global_load_lds staged B, double-buffered, 1 barrier/chunk.
#define K1_THREADS 512

#define K1_STAGE(C, BUF) do{                                                   \
  const unsigned short* _gB = Bfrag + (size_t)(C)*(K1_UNITS*8);                \
  unsigned short* _l = &Bs[BUF][0];                                            \
  gload16(_l + (wid*64)*8,      _gB + (size_t)(tid)*8);                        \
  gload16(_l + (wid*64+512)*8,  _gB + (size_t)(tid+512)*8);                    \
  if (wid < 2)                                                                 \
    gload16(_l + (wid*64+1024)*8, _gB + (size_t)(tid+1024)*8);                 \
}while(0)

#define K1_ALOAD(C, ARA, ARB) do{                                              \
  const float* _ap = aptr + (C)*32;                                            \
  ARA = *(const float4*)(_ap);                                                 \
  ARB = *(const float4*)(_ap + 4);                                             \
}while(0)

#define K1_COMPUTE(BUF, ARA, ARB) do{                                          \
  short8 _ah, _al;                                                             \
  {                                                                            \
    float _va[8] = {ARA.x,ARA.y,ARA.z,ARA.w,ARB.x,ARB.y,ARB.z,ARB.w};          \
    _Pragma("unroll")                                                          \
    for (int _j=0;_j<8;_j++){                                                  \
      unsigned short _h = f2bf(_va[_j]);                                       \
      _ah[_j] = (short)_h;                                                     \
      _al[_j] = (short)f2bf(_va[_j] - bf2f(_h));                               \
    }                                                                          \
  }                                                                            \
  const unsigned short* _sb = &Bs[BUF][0];                                     \
  _Pragma("unroll")                                                            \
  for (int _t=0;_t<5;_t++){                                                    \
    if (_t < nt){                                                              \
      int _row = (t0+_t)*16 + lrow;                                            \
      short8 _bh = *(const short8*)(_sb + _row*32 + quad*8);                   \
      short8 _bl = *(const short8*)(_sb + (_row+144)*32 + quad*8);             \
      acc[_t] = __builtin_amdgcn_mfma_f32_16x16x32_bf16(_ah, _bh, acc[_t], 0,0,0); \
      acc[_t] = __builtin_amdgcn_mfma_f32_16x16x32_bf16(_ah, _bl, acc[_t], 0,0,0); \
      acc[_t] = __builtin_amdgcn_mfma_f32_16x16x32_bf16(_al, _bh, acc[_t], 0,0,0); \
    }                                                                          \
  }                                                                            \
}while(0)

__global__ __launch_bounds__(512, 4) void k1_mfma(const float* __restrict__ u,
    const unsigned short* __restrict__ Bfrag,
    const float* __restrict__ Wpb, float* __restrict__ vb){
  __shared__ unsigned short Bs[2][K1_UNITS*8];   // 2 x 18KB, linear unit order

  const int tid  = threadIdx.x;
  const int wid  = tid >> 6;
  const int lane = tid & 63;
  const int quad = lane >> 4;
  const int lrow = lane & 15;
  const int wm   = wid & 3;          // row subtile: rows wm*16..+15
  const int wn   = wid >> 2;         // n-group: 0 -> tiles 0..4, 1 -> tiles 5..8
  const int t0   = wn ? 5 : 0;
  const int nt   = wn ? 4 : 5;
  const int m0   = blockIdx.x * 64;

  const float* aptr = u + (size_t)(m0 + wm*16 + lrow)*DMODEL + quad*8;

  f32x4 acc[5];
  #pragma unroll
  for (int t=0;t<5;t++) acc[t] = (f32x4){0.f,0.f,0.f,0.f};

  float4 a0a, a0b, a1a, a1b;

  // prologue: DMA chunk 0 into buf 0; A chunk 0 into set 0
  K1_STAGE(0, 0);
  K1_ALOAD(0, a0a, a0b);
  __syncthreads();                                  // vmcnt(0) drain + barrier

  for (int c=0; c<DMODEL/32; c+=2){
    K1_STAGE(c+1, 1);
    K1_ALOAD(c+1, a1a, a1b);
    K1_COMPUTE(0, a0a, a0b);
    __syncthreads();
    if (c+2 < DMODEL/32){
      K1_STAGE(c+2, 0);
      K1_ALOAD(c+2, a0a, a0b);
    }
    K1_COMPUTE(1, a1a, a1b);
    if (c+2 < DMODEL/32) __syncthreads();
  }

  // ---- store: lane L reg i -> row quad*4+i, col lrow (bias in epilogue) ----
  #pragma unroll
  for (int t=0;t<5;t++){
    if (t < nt){
      int col = (t0+t)*16 + lrow;
      if (col < VB_STRIDE){
        float bias = (col < 120) ? Wpb[col] : 0.f;
        #pragma unroll
        for (int i=0;i<4;i++){
          int row = m0 + wm*16 + quad*4 + i;
          vb[(size_t)row*VB_STRIDE + col] = acc[t][i] + bias;
        }
      }
    }
  }
}

// ---------------- K2: A -> power-iter sigma -> scale -> W ; ortho accum ----------------
// v3: merged matmul  W = I - 2A + 2S + (S-2A)@S   (one fewer 16^3 matmul, 16 fewer
// live VGPRs -> compiler can pipeline ds_reads), single LDS buffer per group
// (A -> S -> W overwritten in place; group = 16 lanes of one wave, wave_sync fences).
__global__ __launch_bounds__(128) void k2_build_w(const float* __restrict__ vb,
    float* __restrict__ Wg, float* __restrict__ ortho){
  __shared__ float Mf[8*324];
  __shared__ float gsum[8];
  const int tid = threadIdx.x;
  const int grp = tid >> 4;
  const int r   = tid & 15;
  const int m   = blockIdx.x*8 + grp;
  float* M = Mf + grp*324;
  const float* vrow = vb + (size_t)m*VB_STRIDE;

  // skew row r in registers
  float a_s[16];
  #pragma unroll
  for (int c=0;c<16;c++){
    float val = 0.f;
    if (c > r)      val =  vrow[r*15 - (r*(r-1))/2 + (c-r-1)];
    else if (c < r) val = -vrow[c*15 - (c*(c-1))/2 + (r-c-1)];
    a_s[c] = val;
  }

  // power iteration (register-only): A^T = -A
  float uv = jax_randn((unsigned)m*16u + (unsigned)r);
  float nn = uv*uv;
  #pragma unroll
  for (int s=1;s<16;s<<=1) nn += __shfl_xor(nn, s, 16);
  uv = uv / fmaxf(sqrtf(nn), 1e-12f);

  float t2 = 0.f;
  #pragma unroll
  for (int it=0; it<2; ++it){
    float t1 = 0.f;
    #pragma unroll
    for (int k=0;k<16;k++) t1 += a_s[k]*__shfl(uv, k, 16);
    t1 = -t1;                                   // A^T u
    nn = t1*t1;
    #pragma unroll
    for (int s=1;s<16;s<<=1) nn += __shfl_xor(nn, s, 16);
    float vvec = t1 / fmaxf(sqrtf(nn), 1e-12f);
    t2 = 0.f;
    #pragma unroll
    for (int k=0;k<16;k++) t2 += a_s[k]*__shfl(vvec, k, 16);  // A v
    nn = t2*t2;
    #pragma unroll
    for (int s=1;s<16;s<<=1) nn += __shfl_xor(nn, s, 16);
    uv = t2 / fmaxf(sqrtf(nn), 1e-12f);
  }
  float sig = uv * t2;
  #pragma unroll
  for (int s=1;s<16;s<<=1) sig += __shfl_xor(sig, s, 16);
  sig = fabsf(sig);
  const float scale = 0.3f / fmaxf(sig, 0.3f);
  #pragma unroll
  for (int k=0;k<16;k++) a_s[k] *= scale;

  // phase 1: buffer <- A
  #pragma unroll
  for (int q=0;q<4;q++)
    *(float4*)(M + r*20 + q*4) = make_float4(a_s[q*4],a_s[q*4+1],a_s[q*4+2],a_s[q*4+3]);
  wave_sync();

  // S = A@A (row r)
  float s_s[16];
  #pragma unroll
  for (int j=0;j<16;j++) s_s[j] = 0.f;
  #pragma unroll
  for (int k=0;k<16;k++){
    #pragma unroll
    for (int q=0;q<4;q++){
      float4 ak = *(const float4*)(M + k*20 + q*4);
      s_s[q*4+0] = fmaf(a_s[k], ak.x, s_s[q*4+0]);
      s_s[q*4+1] = fmaf(a_s[k], ak.y, s_s[q*4+1]);
      s_s[q*4+2] = fmaf(a_s[k], ak.z, s_s[q*4+2]);
      s_s[q*4+3] = fmaf(a_s[k], ak.w, s_s[q*4+3]);
    }
  }
  wave_sync();   // all reads of A complete before overwrite

  // phase 2: buffer <- S
  #pragma unroll
  for (int q=0;q<4;q++)
    *(float4*)(M + r*20 + q*4) = make_float4(s_s[q*4],s_s[q*4+1],s_s[q*4+2],s_s[q*4+3]);
  wave_sync();

  // C = (S - 2A)@S  (coef in registers), then W = I - 2A + 2S + C
  float c_s[16];
  #pragma unroll
  for (int j=0;j<16;j++) c_s[j] = 0.f;
  #pragma unroll
  for (int k=0;k<16;k++){
    float ck = s_s[k] - 2.f*a_s[k];
    #pragma unroll
    for (int q=0;q<4;q++){
      float4 sk = *(const float4*)(M + k*20 + q*4);
      c_s[q*4+0] = fmaf(ck, sk.x, c_s[q*4+0]);
      c_s[q*4+1] = fmaf(ck, sk.y, c_s[q*4+1]);
      c_s[q*4+2] = fmaf(ck, sk.z, c_s[q*4+2]);
      c_s[q*4+3] = fmaf(ck, sk.w, c_s[q*4+3]);
    }
  }
  float w_s[16];
  #pragma unroll
  for (int j=0;j<16;j++){
    float wv = -2.f*a_s[j] + 2.f*s_s[j] + c_s[j];
    if (j == r) wv += 1.f;
    w_s[j] = wv;
  }
  float4* wout = (float4*)(Wg + (size_t)m*256 + r*16);
  #pragma unroll
  for (int q=0;q<4;q++)
    wout[q] = make_float4(w_s[q*4],w_s[q*4+1],w_s[q*4+2],w_s[q*4+3]);
  wave_sync();   // all reads of S complete before overwrite

  // phase 3: buffer <- W ; ortho dev
  #pragma unroll
  for (int q=0;q<4;q++)
    *(float4*)(M + r*20 + q*4) = make_float4(w_s[q*4],w_s[q*4+1],w_s[q*4+2],w_s[q*4+3]);
  wave_sync();
  float wt_s[16];
  #pragma unroll
  for (int j=0;j<16;j++) wt_s[j] = 0.f;
  #pragma unroll
  for (int k=0;k<16;k++){
    float ck = M[k*20 + r];                 // W[k][r]
    #pragma unroll
    for (int q=0;q<4;q++){
      float4 wk = *(const float4*)(M + k*20 + q*4);
      wt_s[q*4+0] = fmaf(ck, wk.x, wt_s[q*4+0]);
      wt_s[q*4+1] = fmaf(ck, wk.y, wt_s[q*4+1]);
      wt_s[q*4+2] = fmaf(ck, wk.z, wt_s[q*4+2]);
      wt_s[q*4+3] = fmaf(ck, wk.w, wt_s[q*4+3]);
    }
  }
  float dev = 0.f;
  #pragma unroll
  for (int j=0;j<16;j++){
    float v = wt_s[j] - ((j==r)?1.f:0.f);
    dev += v*v;
  }
  #pragma unroll
  for (int s=1;s<16;s<<=1) dev += __shfl_xor(dev, s, 16);
  if (r==0) gsum[grp] = sqrtf(dev);
  __syncthreads();                           // cross-wave: real barrier
  if (tid==0){
    float t=0.f;
    #pragma unroll
    for (int i=0;i<8;i++) t += gsum[i];
    atomicAdd(ortho, t);
  }
}

// ---------------- K3a: per-chunk reduce in fp64 ----------------
__global__ __launch_bounds__(64) void k3a_chunk_reduce(const float* __restrict__ Wg,
    const float* __restrict__ vb, double* __restrict__ Msum){
  const int chunk = blockIdx.x;
  const int b = chunk / CHUNKS, c = chunk - b*CHUNKS;
  const int lane = threadIdx.x, r = lane & 15, g = lane >> 4;
  __shared__ double Mb[2][16*20];
  __shared__ double sb[16];
  #pragma unroll
  for (int cc=0;cc<4;cc++) Mb[0][r*20 + 4*g + cc] = (r == 4*g+cc) ? 1.0 : 0.0;
  if (lane < 16) sb[lane] = 0.0;
  __syncthreads();
  const size_t mbase = (size_t)b*SEQN + (size_t)c*CLEN;
  float4 wq = *(const float4*)(Wg + mbase*256 + r*16 + 4*g);
  float bx = vb[mbase*VB_STRIDE + 120 + r];
  int p = 0;
  for (int t=0;t<CLEN;++t){
    float4 wn = make_float4(0.f,0.f,0.f,0.f); float bxn = 0.f;
    if (t+1 < CLEN){
      wn  = *(const float4*)(Wg + (mbase+t+1)*256 + r*16 + 4*g);
      bxn = vb[(mbase+t+1)*VB_STRIDE + 120 + r];
    }
    const double* M = Mb[p];
    double a0=0.0,a1=0.0,a2=0.0,a3=0.0, sacc=0.0;
    #pragma unroll
    for (int kg=0;kg<4;kg++){
      float wk0 = __shfl(wq.x, r + 16*kg);
      float wk1 = __shfl(wq.y, r + 16*kg);
      float wk2 = __shfl(wq.z, r + 16*kg);
      float wk3 = __shfl(wq.w, r + 16*kg);
      float wkv[4] = {wk0,wk1,wk2,wk3};
      #pragma unroll
      for (int e=0;e<4;e++){
        int k = 4*kg + e;
        double w = (double)wkv[e];
        const double* mrow = M + k*20 + 4*g;
        a0 = fma(w, mrow[0], a0);
        a1 = fma(w, mrow[1], a1);
        a2 = fma(w, mrow[2], a2);
        a3 = fma(w, mrow[3], a3);
        sacc = fma(w, sb[k], sacc);
      }
    }
    __syncthreads();
    double* Mn = Mb[1-p];
    Mn[r*20+4*g+0]=a0; Mn[r*20+4*g+1]=a1; Mn[r*20+4*g+2]=a2; Mn[r*20+4*g+3]=a3;
    if (g==0) sb[r] = sacc + (double)bx;
    __syncthreads();
    p ^= 1;
    wq = wn; bx = bxn;
  }
  double* out = Msum + (size_t)chunk*272;
  #pragma unroll
  for (int cc=0;cc<4;cc++) out[r*16+4*g+cc] = Mb[p][r*20+4*g+cc];
  if (lane<16) out[256+lane] = sb[lane];
}

// ---------------- K3b: exclusive affine prefix over chunk summaries, fp64 ----------------
__global__ __launch_bounds__(64) void k3b_prefix(const double* __restrict__ Msum,
    double* __restrict__ hstart){
  const int b = blockIdx.x;
  const int lane = threadIdx.x, r = lane & 15, g = lane >> 4;
  __shared__ double q[16];
  if (lane < 16) q[lane] = 0.0;
  __syncthreads();
  const double* base = Msum + (size_t)b*CHUNKS*272;
  double2 m01 = *(const double2*)(base + r*16 + 4*g);
  double2 m23 = *(const double2*)(base + r*16 + 4*g + 2);
  double sv = base[256 + r];
  for (int c=0;c<CHUNKS;++c){
    double2 n01, n23; double svn = 0.0;
    n01.x=n01.y=n23.x=n23.y=0.0;
    if (c+1 < CHUNKS){
      const double* bn = base + (size_t)(c+1)*272;
      n01 = *(const double2*)(bn + r*16 + 4*g);
      n23 = *(const double2*)(bn + r*16 + 4*g + 2);
      svn = bn[256 + r];
    }
    if (lane < 16) hstart[((size_t)b*CHUNKS + c)*16 + lane] = q[lane];
    double part = m01.x*q[4*g+0] + m01.y*q[4*g+1] + m23.x*q[4*g+2] + m23.y*q[4*g+3];
    part += __shfl_xor(part, 16);
    part += __shfl_xor(part, 32);
    __syncthreads();
    if (g==0) q[r] = part + sv;
    __syncthreads();
    m01 = n01; m23 = n23; sv = svn;
  }
}

// ---------------- K3c: re-apply within chunk, fp64 state ----------------
__global__ __launch_bounds__(64) void k3c_apply(const float* __restrict__ Wg,
    const float* __restrict__ vb, const double* __restrict__ hstart,
    float* __restrict__ hout){
  const int chunk = blockIdx.x;
  const int b = chunk / CHUNKS, c = chunk - b*CHUNKS;
  const int lane = threadIdx.x, r = lane & 15, g = lane >> 4;
  __shared__ double h[16];
  if (lane < 16) h[lane] = hstart[(size_t)chunk*16 + lane];
  __syncthreads();
  const size_t mbase = (size_t)b*SEQN + (size_t)c*CLEN;
  float4 wq = *(const float4*)(Wg + mbase*256 + r*16 + 4*g);
  float bx = vb[mbase*VB_STRIDE + 120 + r];
  for (int t=0;t<CLEN;++t){
    float4 wn = make_float4(0.f,0.f,0.f,0.f); float bxn = 0.f;
    if (t+1 < CLEN){
      wn  = *(const float4*)(Wg + (mbase+t+1)*256 + r*16 + 4*g);
      bxn = vb[(mbase+t+1)*VB_STRIDE + 120 + r];
    }
    double part = (double)wq.x*h[4*g+0] + (double)wq.y*h[4*g+1]
                + (double)wq.z*h[4*g+2] + (double)wq.w*h[4*g+3];
    part += __shfl_xor(part, 16);
    part += __shfl_xor(part, 32);
    __syncthreads();
    if (g==0){
      double nh = part + (double)bx;
      h[r] = nh;
      hout[(mbase+t)*16 + r] = (float)nh;
    }
    __syncthreads();
    wq = wn; bx = bxn;
  }
}

// ---------------- K4: y = h @ C^T + u*D ; append ortho_dev ----------------
__device__ __forceinline__ float dot4f(float4 a, float4 b){
  return a.x*b.x + a.y*b.y + a.z*b.z + a.w*b.w;
}

__global__ __launch_bounds__(256) void k4_out(const float* __restrict__ hbuf,
    const float* __restrict__ u, const float* __restrict__ Cw,
    const float* __restrict__ D, const float* __restrict__ ortho,
    float* __restrict__ y, int write_ortho){
  __shared__ float hl[256];
  const int m0 = blockIdx.x * 16;
  hl[threadIdx.x] = hbuf[(size_t)m0*16 + threadIdx.x];
  __syncthreads();
  const int col = threadIdx.x * 4;
  float4 cm[4][4];
  #pragma unroll
  for (int cc=0;cc<4;cc++)
    #pragma unroll
    for (int jj=0;jj<4;jj++)
      cm[cc][jj] = *(const float4*)(Cw + (size_t)(col+cc)*16 + jj*4);
  float4 d4 = *(const float4*)(D + col);
  #pragma unroll
  for (int row=0;row<16;row++){
    const float4* hr = (const float4*)(hl + row*16);
    float4 h0=hr[0], h1=hr[1], h2=hr[2], h3=hr[3];
    float4 o;
    o.x = dot4f(cm[0][0],h0)+dot4f(cm[0][1],h1)+dot4f(cm[0][2],h2)+dot4f(cm[0][3],h3);
    o.y = dot4f(cm[1][0],h0)+dot4f(cm[1][1],h1)+dot4f(cm[1][2],h2)+dot4f(cm[1][3],h3);
    o.z = dot4f(cm[2][0],h0)+dot4f(cm[2][1],h1)+dot4f(cm[2][2],h2)+dot4f(cm[2][3],h3);
    o.w = dot4f(cm[3][0],h0)+dot4f(cm[3][1],h1)+dot4f(cm[3][2],h2)+dot4f(cm[3][3],h3);
    size_t off = (size_t)(m0+row)*DMODEL + col;
    float4 u4 = *(const float4*)(u + off);
    o.x += u4.x*d4.x; o.y += u4.y*d4.y; o.z += u4.z*d4.z; o.w += u4.w*d4.w;
    *(float4*)(y + off) = o;
  }
  if (write_ortho && blockIdx.x==0 && threadIdx.x==0)
    y[YSIZE] = ortho[0] * (1.0f/32768.0f);
}

// ---------------- launcher ----------------
extern "C" void kernel_launch(void* const* d_in, const int* in_sizes, int n_in,
                              void* d_out, int out_size, void* d_ws, size_t ws_size,
                              hipStream_t stream){
  const float* u   = (const float*)d_in[0];
  const float* Wp  = (const float*)d_in[1];
  const float* Wpb = (const float*)d_in[2];
  const float* Bw  = (const float*)d_in[3];
  const float* Cw  = (const float*)d_in[4];
  const float* D   = (const float*)d_in[5];
  float* y = (float*)d_out;

  float* f      = (float*)d_ws;
  float* vb     = f;                                    // 32768*136 f
  float* Wg     = vb  + (size_t)MTOT*VB_STRIDE;         // 32768*256 f
  float* hbuf   = Wg  + (size_t)MTOT*256;               // 32768*16 f
  double* Msum  = (double*)(hbuf + (size_t)MTOT*16);    // BATCHN*CHUNKS*272 d
  double* hstart= Msum + (size_t)BATCHN*CHUNKS*272;     // BATCHN*CHUNKS*16 d
  unsigned short* Bfrag = (unsigned short*)(hstart + (size_t)BATCHN*CHUNKS*16); // 32*1152*8 us
  float* ortho  = (float*)(Bfrag + (size_t)32*K1_UNITS*8);

  int write_ortho = ((size_t)out_size > YSIZE) ? 1 : 0;

  hipMemsetAsync(ortho, 0, sizeof(float), stream);
  hipLaunchKernelGGL(k0_presplit,     dim3((BN_ROWS*DMODEL/4+255)/256), dim3(256), 0, stream, Wp, Bw, Bfrag);
  hipLaunchKernelGGL(k1_mfma,         dim3(MTOT/64), dim3(K1_THREADS), 0, stream, u, Bfrag, Wpb, vb);
  hipLaunchKernelGGL(k2_build_w,      dim3(MTOT/8), dim3(128), 0, stream, vb, Wg, ortho);
  hipLaunchKernelGGL(k3a_chunk_reduce,dim3(BATCHN*CHUNKS), dim3(64), 0, stream, Wg, vb, Msum);
  hipLaunchKernelGGL(k3b_prefix,      dim3(BATCHN), dim3(64), 0, stream, Msum, hstart);
  hipLaunchKernelGGL(k3c_apply,       dim3(BATCHN*CHUNKS), dim3(64), 0, stream, Wg, vb, hstart, hbuf);
  hipLaunchKernelGGL(k4_out,          dim3(MTOT/16), dim3(256), 0, stream, hbuf, u, Cw, D, ortho, y, write_ortho);
}

// Round 7
// 455.996 us; speedup vs baseline: 1.0452x; 1.0144x over previous
//
#include <hip/hip_runtime.h>
#include <hip/hip_bf16.h>
#include <math.h>

#define BATCHN 8
#define SEQN 4096
#define DMODEL 1024
#define MTOT (BATCHN*SEQN)      // 32768
#define VB_STRIDE 136           // 120 skew params | 16 Bx
#define CHUNKS 128
#define CLEN 32
#define YSIZE ((size_t)MTOT*DMODEL)
#define BN_ROWS 144             // 136 padded to 9*16
#define K1_UNITS 1152           // (hi 144 + lo 144) rows * 4 units of 16B per chunk

typedef __attribute__((ext_vector_type(8))) short short8;
typedef __attribute__((ext_vector_type(4))) float f32x4;

__device__ __forceinline__ unsigned short f2bf(float x){
  __hip_bfloat16 h = __float2bfloat16(x);
  return *(unsigned short*)&h;
}
__device__ __forceinline__ float bf2f(unsigned short b){
  __hip_bfloat16 h; *(unsigned short*)&h = b;
  return __bfloat162float(h);
}

// 16B global->LDS direct DMA (wave-uniform LDS base + lane*16; per-lane global addr)
__device__ __forceinline__ void gload16(unsigned short* lds, const unsigned short* g){
  __builtin_amdgcn_global_load_lds(
      (const __attribute__((address_space(1))) unsigned int*)g,
      (__attribute__((address_space(3))) unsigned int*)lds,
      16, 0, 0);
}

// Wave-local LDS fence (k2: all sharing is within one wave; DS ops in-order per wave)
__device__ __forceinline__ void wave_sync(){
  __builtin_amdgcn_sched_barrier(0);
  asm volatile("s_waitcnt lgkmcnt(0)" ::: "memory");
  __builtin_amdgcn_sched_barrier(0);
}

// ---------------- threefry2x32 (partitionable) + XLA erfinv ----------------
__device__ __forceinline__ unsigned rotl32(unsigned x, int d){ return (x<<d)|(x>>(32-d)); }
__device__ __forceinline__ void tfr(unsigned &x0, unsigned &x1, int r){ x0 += x1; x1 = rotl32(x1,r); x1 ^= x0; }

__device__ __forceinline__ float xla_erfinv(float x){
  float w = -log1pf(-x*x);
  float p;
  if (w < 5.0f){
    w = w - 2.5f;
    p = 2.81022636e-08f;
    p = fmaf(p, w, 3.43273939e-07f);
    p = fmaf(p, w, -3.5233877e-06f);
    p = fmaf(p, w, -4.39150654e-06f);
    p = fmaf(p, w, 0.00021858087f);
    p = fmaf(p, w, -0.00125372503f);
    p = fmaf(p, w, -0.00417768164f);
    p = fmaf(p, w, 0.246640727f);
    p = fmaf(p, w, 1.50140941f);
  } else {
    w = sqrtf(w) - 3.0f;
    p = -0.000200214257f;
    p = fmaf(p, w, 0.000100950558f);
    p = fmaf(p, w, 0.00134934322f);
    p = fmaf(p, w, -0.00367342844f);
    p = fmaf(p, w, 0.00573950773f);
    p = fmaf(p, w, -0.0076224613f);
    p = fmaf(p, w, 0.00943887047f);
    p = fmaf(p, w, 1.00167406f);
    p = fmaf(p, w, 2.83297682f);
  }
  return p * x;
}

__device__ float jax_randn(unsigned I){
  unsigned x0 = 0u, x1 = I;
  const unsigned ks2 = 0x1BD11BDBu;
  x0 += 0u; x1 += 1u;
  tfr(x0,x1,13); tfr(x0,x1,15); tfr(x0,x1,26); tfr(x0,x1,6);
  x0 += 1u; x1 += ks2 + 1u;
  tfr(x0,x1,17); tfr(x0,x1,29); tfr(x0,x1,16); tfr(x0,x1,24);
  x0 += ks2; x1 += 0u + 2u;
  tfr(x0,x1,13); tfr(x0,x1,15); tfr(x0,x1,26); tfr(x0,x1,6);
  x0 += 0u; x1 += 1u + 3u;
  tfr(x0,x1,17); tfr(x0,x1,29); tfr(x0,x1,16); tfr(x0,x1,24);
  x0 += 1u; x1 += ks2 + 4u;
  tfr(x0,x1,13); tfr(x0,x1,15); tfr(x0,x1,26); tfr(x0,x1,6);
  x0 += ks2; x1 += 0u + 5u;
  unsigned bits = x0 ^ x1;
  unsigned fb = (bits >> 9) | 0x3f800000u;
  float f = __uint_as_float(fb) - 1.0f;
  const float lo = -0.99999994f;
  float val = f * 2.0f + lo;
  val = fmaxf(lo, val);
  return 1.4142135381698608f * xla_erfinv(val);
}

// ---------------- K0: pre-split [Wp|Bw|0] into bf16 hi/lo, chunk-major UNIT layout ----
__global__ __launch_bounds__(256) void k0_presplit(const float* __restrict__ Wp,
    const float* __restrict__ Bw, unsigned short* __restrict__ Bfrag){
  int i = blockIdx.x*256 + threadIdx.x;      // one thread per 4 elements
  if (i >= BN_ROWS*DMODEL/4) return;
  int n = i >> 8;                            // row 0..143
  int k = (i & 255) * 4;
  float4 t4 = make_float4(0.f,0.f,0.f,0.f);
  if (n < 120)      t4 = *(const float4*)(Wp + (size_t)n*DMODEL + k);
  else if (n < 136) t4 = *(const float4*)(Bw + (size_t)(n-120)*DMODEL + k);
  unsigned short h[4], l[4];
  float v[4] = {t4.x,t4.y,t4.z,t4.w};
  #pragma unroll
  for (int j=0;j<4;j++){
    h[j] = f2bf(v[j]);
    l[j] = f2bf(v[j] - bf2f(h[j]));
  }
  int c  = k >> 5;
  int q  = (k >> 3) & 3;
  int jj = k & 7;                            // 0 or 4
  size_t base = (size_t)c*K1_UNITS*8;
  *(ushort4*)(Bfrag + base + (size_t)(n*4+q)*8 + jj)        = make_ushort4(h[0],h[1],h[2],h[3]);
  *(ushort4*)(Bfrag + base + (size_t)((n+144)*4+q)*8 + jj)  = make_ushort4(l[0],l[1],l[2],l[3]);
}

// ---------------- K1: vb = u @ [Wp|Bw]^T + bias via split-bf16 MFMA ----------------
// v6: 3-buffer pipeline with COUNTED vmcnt (T4). Stage chunk c+2 while computing c;
// s_waitcnt vmcnt(5) at the barrier drains exactly S(c+1)+A(c+1) (a full compute
// phase old) instead of the just-issued DMA. Staging remapped to 144 units/wave
// (2 full gloads + 1 lane<16-masked) so every wave has exactly 3 DMA + 2 A-loads
// outstanding per chunk -> uniform vmcnt arithmetic. sched_barrier(0) brackets
// every fence/barrier (rule #18). MFMA order identical -> vb bitwise same.
#define K1_THREADS 512

#define K1_STAGE(C, BUF) do{                                                   \
  const unsigned short* _gB = Bfrag + (size_t)(C)*(K1_UNITS*8);                \
  unsigned short* _l = &Bs[0][0] + (size_t)(BUF)*(K1_UNITS*8);                 \
  const int _u = wid*144;                                                      \
  gload16(_l + (size_t)_u*8,        _gB + (size_t)(_u+lane)*8);                \
  gload16(_l + (size_t)(_u+64)*8,   _gB + (size_t)(_u+64+lane)*8);             \
  if (lane < 16)                                                               \
    gload16(_l + (size_t)(_u+128)*8, _gB + (size_t)(_u+128+lane)*8);           \
}while(0)

#define K1_ALOAD(C, ARA, ARB) do{                                              \
  const float* _ap = aptr + (C)*32;                                            \
  ARA = *(const float4*)(_ap);                                                 \
  ARB = *(const float4*)(_ap + 4);                                             \
}while(0)

#define K1_FENCE(N) do{                                                       \
  __builtin_amdgcn_sched_barrier(0);                                          \
  asm volatile("s_waitcnt vmcnt(" #N ")" ::: "memory");                       \
  __builtin_amdgcn_sched_barrier(0);                                          \
}while(0)

#define K1_BAR() do{                                                          \
  __builtin_amdgcn_s_barrier();                                               \
  __builtin_amdgcn_sched_barrier(0);                                          \
}while(0)

#define K1_COMPUTE(BUF, ARA, ARB) do{                                          \
  short8 _ah, _al;                                                             \
  {                                                                            \
    float _va[8] = {ARA.x,ARA.y,ARA.z,ARA.w,ARB.x,ARB.y,ARB.z,ARB.w};          \
    _Pragma("unroll")                                                          \
    for (int _j=0;_j<8;_j++){                                                  \
      unsigned short _h = f2bf(_va[_j]);                                       \
      _ah[_j] = (short)_h;                                                     \
      _al[_j] = (short)f2bf(_va[_j] - bf2f(_h));                               \
    }                                                                          \
  }                                                                            \
  const unsigned short* _sb = &Bs[0][0] + (size_t)(BUF)*(K1_UNITS*8);          \
  _Pragma("unroll")                                                            \
  for (int _t=0;_t<5;_t++){                                                    \
    if (_t < nt){                                                              \
      int _row = (t0+_t)*16 + lrow;                                            \
      short8 _bh = *(const short8*)(_sb + _row*32 + quad*8);                   \
      short8 _bl = *(const short8*)(_sb + (_row+144)*32 + quad*8);             \
      acc[_t] = __builtin_amdgcn_mfma_f32_16x16x32_bf16(_ah, _bh, acc[_t], 0,0,0); \
      acc[_t] = __builtin_amdgcn_mfma_f32_16x16x32_bf16(_ah, _bl, acc[_t], 0,0,0); \
      acc[_t] = __builtin_amdgcn_mfma_f32_16x16x32_bf16(_al, _bh, acc[_t], 0,0,0); \
    }                                                                          \
  }                                                                            \
}while(0)

__global__ __launch_bounds__(512, 4) void k1_mfma(const float* __restrict__ u,
    const unsigned short* __restrict__ Bfrag,
    const float* __restrict__ Wpb, float* __restrict__ vb){
  __shared__ unsigned short Bs[3][K1_UNITS*8];   // 3 x 18KB, linear unit order

  const int tid  = threadIdx.x;
  const int wid  = tid >> 6;
  const int lane = tid & 63;
  const int quad = lane >> 4;
  const int lrow = lane & 15;
  const int wm   = wid & 3;          // row subtile: rows wm*16..+15
  const int wn   = wid >> 2;         // n-group: 0 -> tiles 0..4, 1 -> tiles 5..8
  const int t0   = wn ? 5 : 0;
  const int nt   = wn ? 4 : 5;
  const int m0   = blockIdx.x * 64;

  const float* aptr = u + (size_t)(m0 + wm*16 + lrow)*DMODEL + quad*8;

  f32x4 acc[5];
  #pragma unroll
  for (int t=0;t<5;t++) acc[t] = (f32x4){0.f,0.f,0.f,0.f};

  float4 a0a, a0b, a1a, a1b;

  // prologue: stage chunks 0,1 ; A chunks 0,1. outstanding = 10; drain oldest 5.
  K1_STAGE(0, 0);
  K1_ALOAD(0, a0a, a0b);
  K1_STAGE(1, 1);
  K1_ALOAD(1, a1a, a1b);
  K1_FENCE(5);                     // S(0)+A(0) landed; S(1)+A(1) in flight
  K1_BAR();

  int cb0 = 0;                     // buffer holding even chunk c
  #pragma unroll 1
  for (int c=0; c<DMODEL/32; c+=2){
    const int bufc  = cb0;
    const int bufn  = (cb0==2) ? 0 : cb0+1;
    const int bufs0 = (cb0>=1) ? cb0-1 : 2;      // (cb0+2)%3
    // even chunk c
    K1_COMPUTE(bufc, a0a, a0b);
    if (c+2 < DMODEL/32){
      K1_STAGE(c+2, bufs0);
      K1_ALOAD(c+2, a0a, a0b);
      K1_FENCE(5);                 // drains S(c+1)+A(c+1); keeps c+2 in flight
    } else {
      K1_FENCE(0);
    }
    K1_BAR();
    // odd chunk c+1
    K1_COMPUTE(bufn, a1a, a1b);
    if (c+3 < DMODEL/32){
      K1_STAGE(c+3, bufc);
      K1_ALOAD(c+3, a1a, a1b);
      K1_FENCE(5);
    } else {
      K1_FENCE(0);
    }
    K1_BAR();
    cb0 = bufs0;
  }

  // ---- store: lane L reg i -> row quad*4+i, col lrow (bias in epilogue) ----
  #pragma unroll
  for (int t=0;t<5;t++){
    if (t < nt){
      int col = (t0+t)*16 + lrow;
      if (col < VB_STRIDE){
        float bias = (col < 120) ? Wpb[col] : 0.f;
        #pragma unroll
        for (int i=0;i<4;i++){
          int row = m0 + wm*16 + quad*4 + i;
          vb[(size_t)row*VB_STRIDE + col] = acc[t][i] + bias;
        }
      }
    }
  }
}

// ---------------- K2: A -> power-iter sigma -> scale -> W ; ortho accum ----------------
// (kept from R6: merged matmul W = I - 2A + 2S + (S-2A)@S, single in-place LDS buffer)
__global__ __launch_bounds__(128) void k2_build_w(const float* __restrict__ vb,
    float* __restrict__ Wg, float* __restrict__ ortho){
  __shared__ float Mf[8*324];
  __shared__ float gsum[8];
  const int tid = threadIdx.x;
  const int grp = tid >> 4;
  const int r   = tid & 15;
  const int m   = blockIdx.x*8 + grp;
  float* M = Mf + grp*324;
  const float* vrow = vb + (size_t)m*VB_STRIDE;

  // skew row r in registers
  float a_s[16];
  #pragma unroll
  for (int c=0;c<16;c++){
    float val = 0.f;
    if (c > r)      val =  vrow[r*15 - (r*(r-1))/2 + (c-r-1)];
    else if (c < r) val = -vrow[c*15 - (c*(c-1))/2 + (r-c-1)];
    a_s[c] = val;
  }

  // power iteration (register-only): A^T = -A
  float uv = jax_randn((unsigned)m*16u + (unsigned)r);
  float nn = uv*uv;
  #pragma unroll
  for (int s=1;s<16;s<<=1) nn += __shfl_xor(nn, s, 16);
  uv = uv / fmaxf(sqrtf(nn), 1e-12f);

  float t2 = 0.f;
  #pragma unroll
  for (int it=0; it<2; ++it){
    float t1 = 0.f;
    #pragma unroll
    for (int k=0;k<16;k++) t1 += a_s[k]*__shfl(uv, k, 16);
    t1 = -t1;                                   // A^T u
    nn = t1*t1;
    #pragma unroll
    for (int s=1;s<16;s<<=1) nn += __shfl_xor(nn, s, 16);
    float vvec = t1 / fmaxf(sqrtf(nn), 1e-12f);
    t2 = 0.f;
    #pragma unroll
    for (int k=0;k<16;k++) t2 += a_s[k]*__shfl(vvec, k, 16);  // A v
    nn = t2*t2;
    #pragma unroll
    for (int s=1;s<16;s<<=1) nn += __shfl_xor(nn, s, 16);
    uv = t2 / fmaxf(sqrtf(nn), 1e-12f);
  }
  float sig = uv * t2;
  #pragma unroll
  for (int s=1;s<16;s<<=1) sig += __shfl_xor(sig, s, 16);
  sig = fabsf(sig);
  const float scale = 0.3f / fmaxf(sig, 0.3f);
  #pragma unroll
  for (int k=0;k<16;k++) a_s[k] *= scale;

  // phase 1: buffer <- A
  #pragma unroll
  for (int q=0;q<4;q++)
    *(float4*)(M + r*20 + q*4) = make_float4(a_s[q*4],a_s[q*4+1],a_s[q*4+2],a_s[q*4+3]);
  wave_sync();

  // S = A@A (row r)
  float s_s[16];
  #pragma unroll
  for (int j=0;j<16;j++) s_s[j] = 0.f;
  #pragma unroll
  for (int k=0;k<16;k++){
    #pragma unroll
    for (int q=0;q<4;q++){
      float4 ak = *(const float4*)(M + k*20 + q*4);
      s_s[q*4+0] = fmaf(a_s[k], ak.x, s_s[q*4+0]);
      s_s[q*4+1] = fmaf(a_s[k], ak.y, s_s[q*4+1]);
      s_s[q*4+2] = fmaf(a_s[k], ak.z, s_s[q*4+2]);
      s_s[q*4+3] = fmaf(a_s[k], ak.w, s_s[q*4+3]);
    }
  }
  wave_sync();   // all reads of A complete before overwrite

  // phase 2: buffer <- S
  #pragma unroll
  for (int q=0;q<4;q++)
    *(float4*)(M + r*20 + q*4) = make_float4(s_s[q*4],s_s[q*4+1],s_s[q*4+2],s_s[q*4+3]);
  wave_sync();

  // C = (S - 2A)@S  (coef in registers), then W = I - 2A + 2S + C
  float c_s[16];
  #pragma unroll
  for (int j=0;j<16;j++) c_s[j] = 0.f;
  #pragma unroll
  for (int k=0;k<16;k++){
    float ck = s_s[k] - 2.f*a_s[k];
    #pragma unroll
    for (int q=0;q<4;q++){
      float4 sk = *(const float4*)(M + k*20 + q*4);
      c_s[q*4+0] = fmaf(ck, sk.x, c_s[q*4+0]);
      c_s[q*4+1] = fmaf(ck, sk.y, c_s[q*4+1]);
      c_s[q*4+2] = fmaf(ck, sk.z, c_s[q*4+2]);
      c_s[q*4+3] = fmaf(ck, sk.w, c_s[q*4+3]);
    }
  }
  float w_s[16];
  #pragma unroll
  for (int j=0;j<16;j++){
    float wv = -2.f*a_s[j] + 2.f*s_s[j] + c_s[j];
    if (j == r) wv += 1.f;
    w_s[j] = wv;
  }
  float4* wout = (float4*)(Wg + (size_t)m*256 + r*16);
  #pragma unroll
  for (int q=0;q<4;q++)
    wout[q] = make_float4(w_s[q*4],w_s[q*4+1],w_s[q*4+2],w_s[q*4+3]);
  wave_sync();   // all reads of S complete before overwrite

  // phase 3: buffer <- W ; ortho dev
  #pragma unroll
  for (int q=0;q<4;q++)
    *(float4*)(M + r*20 + q*4) = make_float4(w_s[q*4],w_s[q*4+1],w_s[q*4+2],w_s[q*4+3]);
  wave_sync();
  float wt_s[16];
  #pragma unroll
  for (int j=0;j<16;j++) wt_s[j] = 0.f;
  #pragma unroll
  for (int k=0;k<16;k++){
    float ck = M[k*20 + r];                 // W[k][r]
    #pragma unroll
    for (int q=0;q<4;q++){
      float4 wk = *(const float4*)(M + k*20 + q*4);
      wt_s[q*4+0] = fmaf(ck, wk.x, wt_s[q*4+0]);
      wt_s[q*4+1] = fmaf(ck, wk.y, wt_s[q*4+1]);
      wt_s[q*4+2] = fmaf(ck, wk.z, wt_s[q*4+2]);
      wt_s[q*4+3] = fmaf(ck, wk.w, wt_s[q*4+3]);
    }
  }
  float dev = 0.f;
  #pragma unroll
  for (int j=0;j<16;j++){
    float v = wt_s[j] - ((j==r)?1.f:0.f);
    dev += v*v;
  }
  #pragma unroll
  for (int s=1;s<16;s<<=1) dev += __shfl_xor(dev, s, 16);
  if (r==0) gsum[grp] = sqrtf(dev);
  __syncthreads();                           // cross-wave: real barrier
  if (tid==0){
    float t=0.f;
    #pragma unroll
    for (int i=0;i<8;i++) t += gsum[i];
    atomicAdd(ortho, t);
  }
}

// ---------------- K3a: per-chunk reduce in fp64 ----------------
__global__ __launch_bounds__(64) void k3a_chunk_reduce(const float* __restrict__ Wg,
    const float* __restrict__ vb, double* __restrict__ Msum){
  const int chunk = blockIdx.x;
  const int b = chunk / CHUNKS, c = chunk - b*CHUNKS;
  const int lane = threadIdx.x, r = lane & 15, g = lane >> 4;
  __shared__ double Mb[2][16*20];
  __shared__ double sb[16];
  #pragma unroll
  for (int cc=0;cc<4;cc++) Mb[0][r*20 + 4*g + cc] = (r == 4*g+cc) ? 1.0 : 0.0;
  if (lane < 16) sb[lane] = 0.0;
  __syncthreads();
  const size_t mbase = (size_t)b*SEQN + (size_t)c*CLEN;
  float4 wq = *(const float4*)(Wg + mbase*256 + r*16 + 4*g);
  float bx = vb[mbase*VB_STRIDE + 120 + r];
  int p = 0;
  for (int t=0;t<CLEN;++t){
    float4 wn = make_float4(0.f,0.f,0.f,0.f); float bxn = 0.f;
    if (t+1 < CLEN){
      wn  = *(const float4*)(Wg + (mbase+t+1)*256 + r*16 + 4*g);
      bxn = vb[(mbase+t+1)*VB_STRIDE + 120 + r];
    }
    const double* M = Mb[p];
    double a0=0.0,a1=0.0,a2=0.0,a3=0.0, sacc=0.0;
    #pragma unroll
    for (int kg=0;kg<4;kg++){
      float wk0 = __shfl(wq.x, r + 16*kg);
      float wk1 = __shfl(wq.y, r + 16*kg);
      float wk2 = __shfl(wq.z, r + 16*kg);
      float wk3 = __shfl(wq.w, r + 16*kg);
      float wkv[4] = {wk0,wk1,wk2,wk3};
      #pragma unroll
      for (int e=0;e<4;e++){
        int k = 4*kg + e;
        double w = (double)wkv[e];
        const double* mrow = M + k*20 + 4*g;
        a0 = fma(w, mrow[0], a0);
        a1 = fma(w, mrow[1], a1);
        a2 = fma(w, mrow[2], a2);
        a3 = fma(w, mrow[3], a3);
        sacc = fma(w, sb[k], sacc);
      }
    }
    __syncthreads();
    double* Mn = Mb[1-p];
    Mn[r*20+4*g+0]=a0; Mn[r*20+4*g+1]=a1; Mn[r*20+4*g+2]=a2; Mn[r*20+4*g+3]=a3;
    if (g==0) sb[r] = sacc + (double)bx;
    __syncthreads();
    p ^= 1;
    wq = wn; bx = bxn;
  }
  double* out = Msum + (size_t)chunk*272;
  #pragma unroll
  for (int cc=0;cc<4;cc++) out[r*16+4*g+cc] = Mb[p][r*20+4*g+cc];
  if (lane<16) out[256+lane] = sb[lane];
}

// ---------------- K3b: exclusive affine prefix over chunk summaries, fp64 ----------------
__global__ __launch_bounds__(64) void k3b_prefix(const double* __restrict__ Msum,
    double* __restrict__ hstart){
  const int b = blockIdx.x;
  const int lane = threadIdx.x, r = lane & 15, g = lane >> 4;
  __shared__ double q[16];
  if (lane < 16) q[lane] = 0.0;
  __syncthreads();
  const double* base = Msum + (size_t)b*CHUNKS*272;
  double2 m01 = *(const double2*)(base + r*16 + 4*g);
  double2 m23 = *(const double2*)(base + r*16 + 4*g + 2);
  double sv = base[256 + r];
  for (int c=0;c<CHUNKS;++c){
    double2 n01, n23; double svn = 0.0;
    n01.x=n01.y=n23.x=n23.y=0.0;
    if (c+1 < CHUNKS){
      const double* bn = base + (size_t)(c+1)*272;
      n01 = *(const double2*)(bn + r*16 + 4*g);
      n23 = *(const double2*)(bn + r*16 + 4*g + 2);
      svn = bn[256 + r];
    }
    if (lane < 16) hstart[((size_t)b*CHUNKS + c)*16 + lane] = q[lane];
    double part = m01.x*q[4*g+0] + m01.y*q[4*g+1] + m23.x*q[4*g+2] + m23.y*q[4*g+3];
    part += __shfl_xor(part, 16);
    part += __shfl_xor(part, 32);
    __syncthreads();
    if (g==0) q[r] = part + sv;
    __syncthreads();
    m01 = n01; m23 = n23; sv = svn;
  }
}

// ---------------- K3c: re-apply within chunk, fp64 state ----------------
__global__ __launch_bounds__(64) void k3c_apply(const float* __restrict__ Wg,
    const float* __restrict__ vb, const double* __restrict__ hstart,
    float* __restrict__ hout){
  const int chunk = blockIdx.x;
  const int b = chunk / CHUNKS, c = chunk - b*CHUNKS;
  const int lane = threadIdx.x, r = lane & 15, g = lane >> 4;
  __shared__ double h[16];
  if (lane < 16) h[lane] = hstart[(size_t)chunk*16 + lane];
  __syncthreads();
  const size_t mbase = (size_t)b*SEQN + (size_t)c*CLEN;
  float4 wq = *(const float4*)(Wg + mbase*256 + r*16 + 4*g);
  float bx = vb[mbase*VB_STRIDE + 120 + r];
  for (int t=0;t<CLEN;++t){
    float4 wn = make_float4(0.f,0.f,0.f,0.f); float bxn = 0.f;
    if (t+1 < CLEN){
      wn  = *(const float4*)(Wg + (mbase+t+1)*256 + r*16 + 4*g);
      bxn = vb[(mbase+t+1)*VB_STRIDE + 120 + r];
    }
    double part = (double)wq.x*h[4*g+0] + (double)wq.y*h[4*g+1]
                + (double)wq.z*h[4*g+2] + (double)wq.w*h[4*g+3];
    part += __shfl_xor(part, 16);
    part += __shfl_xor(part, 32);
    __syncthreads();
    if (g==0){
      double nh = part + (double)bx;
      h[r] = nh;
      hout[(mbase+t)*16 + r] = (float)nh;
    }
    __syncthreads();
    wq = wn; bx = bxn;
  }
}

// ---------------- K4: y = h @ C^T + u*D ; append ortho_dev ----------------
__device__ __forceinline__ float dot4f(float4 a, float4 b){
  return a.x*b.x + a.y*b.y + a.z*b.z + a.w*b.w;
}

__global__ __launch_bounds__(256) void k4_out(const float* __restrict__ hbuf,
    const float* __restrict__ u, const float* __restrict__ Cw,
    const float* __restrict__ D, const float* __restrict__ ortho,
    float* __restrict__ y, int write_ortho){
  __shared__ float hl[256];
  const int m0 = blockIdx.x * 16;
  hl[threadIdx.x] = hbuf[(size_t)m0*16 + threadIdx.x];
  __syncthreads();
  const int col = threadIdx.x * 4;
  float4 cm[4][4];
  #pragma unroll
  for (int cc=0;cc<4;cc++)
    #pragma unroll
    for (int jj=0;jj<4;jj++)
      cm[cc][jj] = *(const float4*)(Cw + (size_t)(col+cc)*16 + jj*4);
  float4 d4 = *(const float4*)(D + col);
  #pragma unroll
  for (int row=0;row<16;row++){
    const float4* hr = (const float4*)(hl + row*16);
    float4 h0=hr[0], h1=hr[1], h2=hr[2], h3=hr[3];
    float4 o;
    o.x = dot4f(cm[0][0],h0)+dot4f(cm[0][1],h1)+dot4f(cm[0][2],h2)+dot4f(cm[0][3],h3);
    o.y = dot4f(cm[1][0],h0)+dot4f(cm[1][1],h1)+dot4f(cm[1][2],h2)+dot4f(cm[1][3],h3);
    o.z = dot4f(cm[2][0],h0)+dot4f(cm[2][1],h1)+dot4f(cm[2][2],h2)+dot4f(cm[2][3],h3);
    o.w = dot4f(cm[3][0],h0)+dot4f(cm[3][1],h1)+dot4f(cm[3][2],h2)+dot4f(cm[3][3],h3);
    size_t off = (size_t)(m0+row)*DMODEL + col;
    float4 u4 = *(const float4*)(u + off);
    o.x += u4.x*d4.x; o.y += u4.y*d4.y; o.z += u4.z*d4.z; o.w += u4.w*d4.w;
    *(float4*)(y + off) = o;
  }
  if (write_ortho && blockIdx.x==0 && threadIdx.x==0)
    y[YSIZE] = ortho[0] * (1.0f/32768.0f);
}

// ---------------- launcher ----------------
extern "C" void kernel_launch(void* const* d_in, const int* in_sizes, int n_in,
                              void* d_out, int out_size, void* d_ws, size_t ws_size,
                              hipStream_t stream){
  const float* u   = (const float*)d_in[0];
  const float* Wp  = (const float*)d_in[1];
  const float* Wpb = (const float*)d_in[2];
  const float* Bw  = (const float*)d_in[3];
  const float* Cw  = (const float*)d_in[4];
  const float* D   = (const float*)d_in[5];
  float* y = (float*)d_out;

  float* f      = (float*)d_ws;
  float* vb     = f;                                    // 32768*136 f
  float* Wg     = vb  + (size_t)MTOT*VB_STRIDE;         // 32768*256 f
  float* hbuf   = Wg  + (size_t)MTOT*256;               // 32768*16 f
  double* Msum  = (double*)(hbuf + (size_t)MTOT*16);    // BATCHN*CHUNKS*272 d
  double* hstart= Msum + (size_t)BATCHN*CHUNKS*272;     // BATCHN*CHUNKS*16 d
  unsigned short* Bfrag = (unsigned short*)(hstart + (size_t)BATCHN*CHUNKS*16); // 32*1152*8 us
  float* ortho  = (float*)(Bfrag + (size_t)32*K1_UNITS*8);

  int write_ortho = ((size_t)out_size > YSIZE) ? 1 : 0;

  hipMemsetAsync(ortho, 0, sizeof(float), stream);
  hipLaunchKernelGGL(k0_presplit,     dim3((BN_ROWS*DMODEL/4+255)/256), dim3(256), 0, stream, Wp, Bw, Bfrag);
  hipLaunchKernelGGL(k1_mfma,         dim3(MTOT/64), dim3(K1_THREADS), 0, stream, u, Bfrag, Wpb, vb);
  hipLaunchKernelGGL(k2_build_w,      dim3(MTOT/8), dim3(128), 0, stream, vb, Wg, ortho);
  hipLaunchKernelGGL(k3a_chunk_reduce,dim3(BATCHN*CHUNKS), dim3(64), 0, stream, Wg, vb, Msum);
  hipLaunchKernelGGL(k3b_prefix,      dim3(BATCHN), dim3(64), 0, stream, Msum, hstart);
  hipLaunchKernelGGL(k3c_apply,       dim3(BATCHN*CHUNKS), dim3(64), 0, stream, Wg, vb, hstart, hbuf);
  hipLaunchKernelGGL(k4_out,          dim3(MTOT/16), dim3(256), 0, stream, hbuf, u, Cw, D, ortho, y, write_ortho);
}